// Round 17
// baseline (1112.035 us; speedup 1.0000x reference)
//
#include <hip/hip_runtime.h>
#include <hip/hip_fp16.h>

#define NN 1048576   // nodes
#define NE 8388608   // edges
#define NG 16384     // graphs
#define NBUCK 256    // dst buckets (4096 nodes each)
#define BSH 12       // bucket shift
#define EPB (NE / 256)   // edges per partition block = 32768

typedef _Float16 half8 __attribute__((ext_vector_type(8)));
typedef float f32x16 __attribute__((ext_vector_type(16)));

// ---------------- node embedding: hA = f16(x @ W_emb^T + b_emb) ----------------
__global__ __launch_bounds__(256) void k_embed(const float* __restrict__ x,
    const float* __restrict__ W, const float* __restrict__ b, __half* __restrict__ h) {
  __shared__ float sW[160];
  __shared__ float sb[32];
  int t = threadIdx.x;
  if (t < 160) sW[t] = W[t];
  if (t < 32) sb[t] = b[t];
  __syncthreads();
  int idx = blockIdx.x * 256 + t;      // (node, channel)
  int c = idx & 31, n = idx >> 5;
  const float* xr = x + n * 5;
  float acc = sb[c];
#pragma unroll
  for (int k = 0; k < 5; ++k) acc = fmaf(xr[k], sW[c * 5 + k], acc);
  h[idx] = __float2half(acc);
}

// ---------------- radix pass 1: per-(block,bucket) histogram ----------------
__global__ __launch_bounds__(256) void k_pcnt(const int* __restrict__ dst, int* __restrict__ hist) {
  __shared__ int lh[NBUCK];
  int t = threadIdx.x;
  lh[t] = 0;
  __syncthreads();
  int base = blockIdx.x * EPB;
  for (int e = base + t; e < base + EPB; e += 256)
    atomicAdd(&lh[dst[e] >> BSH], 1);
  __syncthreads();
  hist[t * 256 + blockIdx.x] = lh[t];
}

// ---------------- radix pass 2a: per-bucket row scan + totals ----------------
__global__ __launch_bounds__(256) void k_scanA(int* __restrict__ hist, int* __restrict__ tot) {
  __shared__ int s2[256];
  int b = blockIdx.x, t = threadIdx.x;
  int v = hist[b * 256 + t];
  s2[t] = v; __syncthreads();
  for (int st = 1; st < 256; st <<= 1) {
    int a = (t >= st) ? s2[t - st] : 0; __syncthreads(); s2[t] += a; __syncthreads();
  }
  hist[b * 256 + t] = s2[t] - v;
  if (t == 255) tot[b] = s2[255];
}

// ---------------- radix pass 2b: scan bucket totals -> gbase ----------------
__global__ __launch_bounds__(256) void k_scanB(const int* __restrict__ tot, int* __restrict__ gbase) {
  __shared__ int s2[256];
  int t = threadIdx.x;
  int c = tot[t];
  s2[t] = c; __syncthreads();
  for (int st = 1; st < 256; st <<= 1) {
    int a = (t >= st) ? s2[t - st] : 0; __syncthreads(); s2[t] += a; __syncthreads();
  }
  gbase[t] = s2[t] - c;
  if (t == 255) gbase[256] = s2[255];
}

// ---- radix pass 3: partition; bS = (src<<12)|dlocal, bW = f16 weight ----
__global__ __launch_bounds__(256) void k_part(const int* __restrict__ ei, const float* __restrict__ ew,
                                              const int* __restrict__ hist, const int* __restrict__ gbase,
                                              unsigned* __restrict__ bS, __half* __restrict__ bW) {
  __shared__ int cur[NBUCK];
  int t = threadIdx.x, blk = blockIdx.x;
  cur[t] = gbase[t] + hist[t * 256 + blk];
  __syncthreads();
  int base = blk * EPB;
  for (int e = base + t; e < base + EPB; e += 256) {
    int src = ei[e];
    int d   = ei[NE + e];
    __half w = __float2half(ew[e]);
    int b = d >> BSH;
    int pos = atomicAdd(&cur[b], 1);
    bS[pos] = ((unsigned)src << 12) | (unsigned)(d & 4095);
    bW[pos] = w;
  }
}

// ------- per-bucket CSR finalize: rowptr + L2-local scatter into srcw/wgt -------
__global__ __launch_bounds__(256) void k_fillD(const int* __restrict__ gbase, const unsigned* __restrict__ bS,
                                               const __half* __restrict__ bW, int* __restrict__ rowptr,
                                               unsigned* __restrict__ srcw, __half* __restrict__ wgt) {
  __shared__ int loc[4096];
  __shared__ int s2[256];
  int t = threadIdx.x, b = blockIdx.x;
  int beg = gbase[b], end = gbase[b + 1], gb = beg;
  int node_base = b << BSH;
#pragma unroll
  for (int j = 0; j < 16; ++j) loc[t * 16 + j] = 0;
  __syncthreads();
  for (int i = beg + t; i < end; i += 256) atomicAdd(&loc[bS[i] & 4095], 1);
  __syncthreads();
  int v[16]; int tsum = 0;
#pragma unroll
  for (int j = 0; j < 16; ++j) { v[j] = loc[t * 16 + j]; tsum += v[j]; }
  s2[t] = tsum; __syncthreads();
  for (int st = 1; st < 256; st <<= 1) {
    int a = (t >= st) ? s2[t - st] : 0; __syncthreads(); s2[t] += a; __syncthreads();
  }
  int run = s2[t] - tsum;
#pragma unroll
  for (int j = 0; j < 16; ++j) {
    loc[t * 16 + j] = run;
    rowptr[node_base + t * 16 + j] = gb + run;
    run += v[j];
  }
  if (b == NBUCK - 1 && t == 255) rowptr[NN] = NE;
  __syncthreads();
  for (int i = beg + t; i < end; i += 256) {
    unsigned r = bS[i];
    __half w = bW[i];
    int p = atomicAdd(&loc[r & 4095], 1);
    srcw[gb + p] = r >> 12;
    wgt[gb + p] = w;
  }
}

// ---------------- graph rowptr from sorted batch ----------------
__global__ __launch_bounds__(256) void k_gbound(const int* __restrict__ batch, int* __restrict__ gptr) {
  int n = blockIdx.x * 256 + threadIdx.x;
  int b = batch[n];
  int prev = (n == 0) ? -1 : batch[n - 1];
  for (int g = prev + 1; g <= b; ++g) gptr[g] = n;
  if (n == NN - 1) {
    for (int g = b + 1; g <= NG; ++g) gptr[g] = NN;
  }
}

// ------ gather-only kernel: low-VGPR, high-occupancy (MLP-bound path) ------
// 32 lanes/node, 8 outstanding 2B loads/lane; optional fused BN+ReLU on input.
template <int FUSE_BN>
__global__ __launch_bounds__(256) void k_gather(
    const int* __restrict__ rowptr, const unsigned* __restrict__ srcw,
    const __half* __restrict__ wgt, const __half* __restrict__ hIn,
    const float* __restrict__ bnss, __half* __restrict__ aggG) {
  __shared__ unsigned sS[256];
  __shared__ __half sW[256];
  int t = threadIdx.x, grp = t >> 5, c = t & 31;
  float bs0 = 0.f, bs1 = 0.f;
  if constexpr (FUSE_BN) { bs0 = bnss[c]; bs1 = bnss[32 + c]; }
  for (int n0 = blockIdx.x * 8; n0 < NN; n0 += gridDim.x * 8) {
    int n = n0 + grp;
    int r0 = rowptr[n], r1 = rowptr[n + 1];
    float acc = 0.f;
    for (int j = r0; j < r1; j += 32) {
      int m_ = r1 - j; if (m_ > 32) m_ = 32;
      unsigned s = 0u; __half w = __ushort_as_half((unsigned short)0);   // pad: src=0, w=+0
      if (c < m_) { s = srcw[j + c]; w = wgt[j + c]; }
      sS[t] = s; sW[t] = w;                        // same-wave LDS: no barrier
      int mm = (m_ + 7) & ~7;
      for (int i = 0; i < mm; i += 8) {
        const uint4* p4 = (const uint4*)&sS[grp * 32 + i];
        uint4 a4 = p4[0], b4 = p4[1];
        half8 w8 = *(const half8*)&sW[grp * 32 + i];
        // 8 independent 2B gathers in flight
        float h0 = __half2float(hIn[(size_t)a4.x * 32 + c]);
        float h1 = __half2float(hIn[(size_t)a4.y * 32 + c]);
        float h2 = __half2float(hIn[(size_t)a4.z * 32 + c]);
        float h3 = __half2float(hIn[(size_t)a4.w * 32 + c]);
        float h4 = __half2float(hIn[(size_t)b4.x * 32 + c]);
        float h5 = __half2float(hIn[(size_t)b4.y * 32 + c]);
        float h6 = __half2float(hIn[(size_t)b4.z * 32 + c]);
        float h7 = __half2float(hIn[(size_t)b4.w * 32 + c]);
        if constexpr (FUSE_BN) {
          h0 = fmaxf(fmaf(h0, bs0, bs1), 0.f); h1 = fmaxf(fmaf(h1, bs0, bs1), 0.f);
          h2 = fmaxf(fmaf(h2, bs0, bs1), 0.f); h3 = fmaxf(fmaf(h3, bs0, bs1), 0.f);
          h4 = fmaxf(fmaf(h4, bs0, bs1), 0.f); h5 = fmaxf(fmaf(h5, bs0, bs1), 0.f);
          h6 = fmaxf(fmaf(h6, bs0, bs1), 0.f); h7 = fmaxf(fmaf(h7, bs0, bs1), 0.f);
        }
        acc = fmaf((float)w8[0], h0, acc);
        acc = fmaf((float)w8[1], h1, acc);
        acc = fmaf((float)w8[2], h2, acc);
        acc = fmaf((float)w8[3], h3, acc);
        acc = fmaf((float)w8[4], h4, acc);
        acc = fmaf((float)w8[5], h5, acc);
        acc = fmaf((float)w8[6], h6, acc);
        acc = fmaf((float)w8[7], h7, acc);
      }
    }
    aggG[(size_t)n * 32 + c] = __float2half(acc);
  }
}

// ------ streaming MFMA dual-linear + BN stats; fragments read directly from global ------
template <int FUSE_BN>
__global__ __launch_bounds__(256) void k_lin(
    const __half* __restrict__ aggG, const __half* __restrict__ hIn,
    const float* __restrict__ bnss, const float* __restrict__ Wrel,
    const float* __restrict__ brel, const float* __restrict__ Wroot,
    __half* __restrict__ hPre, double* __restrict__ stats) {
  __shared__ float sBn[64];
  __shared__ double rS[256], rQ[256];
  int t = threadIdx.x;
  int wv = t >> 6, lane = t & 63;
  int c = lane & 31, hi = lane >> 5;
  if (FUSE_BN && t < 64) sBn[t] = bnss[t];
  __syncthreads();
  // B fragments in registers: B[k][c], k = 16m + hi*8 + j
  half8 bfr[4];
#pragma unroll
  for (int m = 0; m < 4; ++m)
#pragma unroll
    for (int j = 0; j < 8; ++j) {
      int k = 16 * m + hi * 8 + j;
      float w = (k < 32) ? Wrel[c * 32 + k] : Wroot[c * 32 + (k - 32)];
      bfr[m][j] = (_Float16)w;
    }
  float bias = brel[c];
  float aS = 0.f, aQ = 0.f;                // <=64 values/thread; double at block reduce

  for (int tile = blockIdx.x * 4 + wv; tile < NN / 32; tile += gridDim.x * 4) {
    int nbase = tile * 32;
    f32x16 d;
#pragma unroll
    for (int r = 0; r < 16; ++r) d[r] = bias;
#pragma unroll
    for (int m = 0; m < 4; ++m) {
      half8 a;
      if (m < 2) {
        a = *(const half8*)(aggG + (size_t)(nbase + c) * 32 + 16 * m + hi * 8);
      } else {
        int chb = 16 * (m - 2) + hi * 8;
        a = *(const half8*)(hIn + (size_t)(nbase + c) * 32 + chb);
        if constexpr (FUSE_BN) {
#pragma unroll
          for (int j = 0; j < 8; ++j) {
            float v = (float)a[j];
            v = fmaxf(fmaf(v, sBn[chb + j], sBn[32 + chb + j]), 0.f);
            a[j] = (_Float16)v;
          }
        }
      }
      d = __builtin_amdgcn_mfma_f32_32x32x16_f16(a, bfr[m], d, 0, 0, 0);
    }
    // D: col=lane&31, row=(r&3)+8*(r>>2)+4*hi
#pragma unroll
    for (int r = 0; r < 16; ++r) {
      int node = (r & 3) + 8 * (r >> 2) + 4 * hi;
      float v = d[r];
      hPre[(size_t)(nbase + node) * 32 + c] = __float2half(v);
      aS += v; aQ += v * v;
    }
  }
  rS[t] = (double)aS; rQ[t] = (double)aQ;
  __syncthreads();
  for (int s = 128; s >= 32; s >>= 1) {
    if (t < s) { rS[t] += rS[t + s]; rQ[t] += rQ[t + s]; }
    __syncthreads();
  }
  if (t < 32) {
    atomicAdd(&stats[t], rS[t]);
    atomicAdd(&stats[32 + t], rQ[t]);
  }
}

// ---------------- finalize BN ----------------
__global__ void k_bnfin(const double* __restrict__ stats, const float* __restrict__ gamma,
                        const float* __restrict__ beta, float* __restrict__ ss) {
  int c = threadIdx.x;
  double mean = stats[c] * (1.0 / NN);
  double var = stats[32 + c] * (1.0 / NN) - mean * mean;
  float scale = gamma[c] * (float)(1.0 / sqrt(var + 1e-5));
  ss[c] = scale;
  ss[32 + c] = beta[c] - (float)mean * scale;
}

// ------- layer-2 BN apply + ReLU + segment-max pool (half2, 4 node-slots) -------
__global__ __launch_bounds__(256) void k_pool(const __half* __restrict__ hB,
    const float* __restrict__ ss, const int* __restrict__ gptr, float* __restrict__ pooled) {
  int t = threadIdx.x;
  int wv = t >> 6, lane = t & 63;
  int p = lane >> 4, cl = lane & 15;          // 4 nodes in flight, 2 ch/lane
  float s0x = ss[2 * cl], s0y = ss[2 * cl + 1];
  float s1x = ss[32 + 2 * cl], s1y = ss[32 + 2 * cl + 1];
  int g = blockIdx.x * 4 + wv;                // grid 4096 x 4 waves = NG exactly
  int a = gptr[g], b = gptr[g + 1];
  float mx = 0.f, my = 0.f;                   // post-ReLU max >= 0
  for (int n = a + p; n < b; n += 4) {
    float2 hv = __half22float2(*(const __half2*)(hB + (size_t)n * 32 + 2 * cl));
    mx = fmaxf(mx, fmaf(hv.x, s0x, s1x));
    my = fmaxf(my, fmaf(hv.y, s0y, s1y));
  }
  mx = fmaxf(mx, __shfl_xor(mx, 16, 64)); my = fmaxf(my, __shfl_xor(my, 16, 64));
  mx = fmaxf(mx, __shfl_xor(mx, 32, 64)); my = fmaxf(my, __shfl_xor(my, 32, 64));
  if (p == 0) *(float2*)&pooled[g * 32 + 2 * cl] = make_float2(mx, my);
}

// ---------------- MLP head ----------------
__global__ __launch_bounds__(256) void k_head(const float* __restrict__ pooled,
    const float* __restrict__ W1, const float* __restrict__ b1,
    const float* __restrict__ W2, const float* __restrict__ b2, float* __restrict__ out) {
  __shared__ float sW1[64 * 33], sW2[10 * 65], sb1[64], sb2[10];
  __shared__ float sHid[4][64];
  int t = threadIdx.x;
  for (int i = t; i < 2048; i += 256) sW1[(i >> 5) * 33 + (i & 31)] = W1[i];
  for (int i = t; i < 640; i += 256) sW2[(i >> 6) * 65 + (i & 63)] = W2[i];
  if (t < 64) sb1[t] = b1[t];
  if (t < 10) sb2[t] = b2[t];
  __syncthreads();
  int w = t >> 6, lane = t & 63;
  for (int g = blockIdx.x * 4 + w; g < NG; g += gridDim.x * 4) {
    float pv = (lane < 32) ? pooled[g * 32 + lane] : 0.f;
    float acc = sb1[lane];
#pragma unroll
    for (int k = 0; k < 32; ++k)
      acc = fmaf(__shfl(pv, k, 64), sW1[lane * 33 + k], acc);
    acc = fmaxf(acc, 0.f);
    sHid[w][lane] = acc;
    __syncthreads();
    if (lane < 10) {
      float o = sb2[lane];
#pragma unroll
      for (int j = 0; j < 64; ++j) o = fmaf(sHid[w][j], sW2[lane * 65 + j], o);
      out[g * 10 + lane] = o;
    }
    __syncthreads();
  }
}

extern "C" void kernel_launch(void* const* d_in, const int* in_sizes, int n_in,
                              void* d_out, int out_size, void* d_ws, size_t ws_size,
                              hipStream_t stream) {
  const float* x      = (const float*)d_in[0];
  const int*   ei     = (const int*)d_in[1];
  const float* ea     = (const float*)d_in[2];
  const int*   batch  = (const int*)d_in[3];
  const float* W_emb  = (const float*)d_in[4];
  const float* b_emb  = (const float*)d_in[5];
  const float* W_rel  = (const float*)d_in[6];
  const float* b_rel  = (const float*)d_in[7];
  const float* W_root = (const float*)d_in[8];
  const float* gamma  = (const float*)d_in[9];
  const float* beta   = (const float*)d_in[10];
  const float* W1     = (const float*)d_in[11];
  const float* b1     = (const float*)d_in[12];
  const float* W2     = (const float*)d_in[13];
  const float* b2     = (const float*)d_in[14];
  float* out = (float*)d_out;

  // ---- workspace layout (~247 MiB of 256 MiB) ----
  char* ws = (char*)d_ws;
  const size_t MiB = 1ull << 20;
  __half*   hA    = (__half*)(ws + 0);            // 64 MiB (embed out; L2 lin out)
  __half*   hB    = (__half*)(ws + 64 * MiB);     // 64 MiB (L1 lin out)
  __half*   aggG  = (__half*)(ws + 128 * MiB);    // 64 MiB (gather out)
  unsigned* bS    = (unsigned*)(ws + 128 * MiB);  // 32 MiB ALIAS aggG (dead before gather)
  __half*   bW    = (__half*)(ws + 160 * MiB);    // 16 MiB ALIAS aggG (dead before gather)
  unsigned* srcw  = (unsigned*)(ws + 192 * MiB);  // 32 MiB
  __half*   wgt   = (__half*)(ws + 224 * MiB);    // 16 MiB
  size_t off = 240 * MiB;
  int*    rowptr = (int*)(ws + off);  off += ((size_t)NN + 64) * 4;   // 4 MiB
  int*    hist   = (int*)(ws + off);  off += (size_t)NBUCK * 256 * 4; // 256 KiB
  int*    tot    = (int*)(ws + off);  off += 1024;
  int*    gbase  = (int*)(ws + off);  off += 2048;
  int*    gptr   = (int*)(ws + off);  off += ((size_t)NG + 64) * 4;
  float*  pooled = (float*)(ws + off);                                 // 2 MiB
  double* stats = (double*)d_out;                   // overwritten by k_head later
  float*  ss0   = (float*)((char*)d_out + 512);
  float*  ss1   = (float*)((char*)d_out + 768);

  k_embed<<<NN * 32 / 256, 256, 0, stream>>>(x, W_emb, b_emb, hA);

  // ---- radix-partition CSR build (split src/wgt arrays) ----
  k_pcnt <<<256, 256, 0, stream>>>(ei + NE, hist);
  k_scanA<<<NBUCK, 256, 0, stream>>>(hist, tot);
  k_scanB<<<1, 256, 0, stream>>>(tot, gbase);
  k_part <<<256, 256, 0, stream>>>(ei, ea, hist, gbase, bS, bW);
  k_fillD<<<NBUCK, 256, 0, stream>>>(gbase, bS, bW, rowptr, srcw, wgt);
  k_gbound<<<NN / 256, 256, 0, stream>>>(batch, gptr);

  // ---- layer 1: gather(hA) -> aggG; lin(aggG, hA) -> hB + stats ----
  (void)hipMemsetAsync(stats, 0, 64 * 8, stream);
  k_gather<0><<<2048, 256, 0, stream>>>(rowptr, srcw, wgt, hA, nullptr, aggG);
  k_lin<0><<<2048, 256, 0, stream>>>(aggG, hA, nullptr, W_rel, b_rel, W_root, hB, stats);
  k_bnfin<<<1, 32, 0, stream>>>(stats, gamma, beta, ss0);

  // ---- layer 2: BN fused into inputs; gather(hB) -> aggG; lin -> hA + stats ----
  (void)hipMemsetAsync(stats, 0, 64 * 8, stream);
  k_gather<1><<<2048, 256, 0, stream>>>(rowptr, srcw, wgt, hB, ss0, aggG);
  k_lin<1><<<2048, 256, 0, stream>>>(aggG, hB, ss0, W_rel + 1024, b_rel + 32,
                                     W_root + 1024, hA, stats);
  k_bnfin<<<1, 32, 0, stream>>>(stats, gamma + 32, beta + 32, ss1);

  k_pool<<<NG / 4, 256, 0, stream>>>(hA, ss1, gptr, pooled);
  k_head<<<1024, 256, 0, stream>>>(pooled, W1, b1, W2, b2, out);
}

// Round 20
// 1022.956 us; speedup vs baseline: 1.0871x; 1.0871x over previous
//
#include <hip/hip_runtime.h>
#include <hip/hip_fp16.h>

#define NN 1048576   // nodes
#define NE 8388608   // edges
#define NG 16384     // graphs
#define NBUCK 1024   // dst buckets (1024 nodes each)
#define BSH 10       // bucket shift
#define PBLK 256     // partition blocks
#define EPB (NE / PBLK)  // edges per partition block = 32768

typedef _Float16 half8 __attribute__((ext_vector_type(8)));
typedef float f32x16 __attribute__((ext_vector_type(16)));

// ---------------- node embedding: hA = f16(x @ W_emb^T + b_emb) ----------------
__global__ __launch_bounds__(256) void k_embed(const float* __restrict__ x,
    const float* __restrict__ W, const float* __restrict__ b, __half* __restrict__ h) {
  __shared__ float sW[160];
  __shared__ float sb[32];
  int t = threadIdx.x;
  if (t < 160) sW[t] = W[t];
  if (t < 32) sb[t] = b[t];
  __syncthreads();
  int idx = blockIdx.x * 256 + t;      // (node, channel)
  int c = idx & 31, n = idx >> 5;
  const float* xr = x + n * 5;
  float acc = sb[c];
#pragma unroll
  for (int k = 0; k < 5; ++k) acc = fmaf(xr[k], sW[c * 5 + k], acc);
  h[idx] = __float2half(acc);
}

// ---------------- radix pass 1: per-(block,bucket) histogram ----------------
__global__ __launch_bounds__(256) void k_pcnt(const int* __restrict__ dst, int* __restrict__ hist) {
  __shared__ int lh[NBUCK];
  int t = threadIdx.x;
#pragma unroll
  for (int k = 0; k < 4; ++k) lh[t + k * 256] = 0;
  __syncthreads();
  int base = blockIdx.x * EPB;
  for (int e = base + t; e < base + EPB; e += 256)
    atomicAdd(&lh[dst[e] >> BSH], 1);
  __syncthreads();
#pragma unroll
  for (int k = 0; k < 4; ++k) {
    int b = t + k * 256;
    hist[b * PBLK + blockIdx.x] = lh[b];           // assign, no atomics
  }
}

// ---------------- radix pass 2a: per-bucket row scan (256 cols) + totals ----------------
__global__ __launch_bounds__(256) void k_scanA(int* __restrict__ hist, int* __restrict__ tot) {
  __shared__ int s2[256];
  int b = blockIdx.x, t = threadIdx.x;
  int v = hist[b * PBLK + t];
  s2[t] = v; __syncthreads();
  for (int st = 1; st < 256; st <<= 1) {
    int a = (t >= st) ? s2[t - st] : 0; __syncthreads(); s2[t] += a; __syncthreads();
  }
  hist[b * PBLK + t] = s2[t] - v;
  if (t == 255) tot[b] = s2[255];
}

// ---------------- radix pass 2b: scan 1024 bucket totals -> gbase ----------------
__global__ __launch_bounds__(256) void k_scanB(const int* __restrict__ tot, int* __restrict__ gbase) {
  __shared__ int s2[256];
  int t = threadIdx.x;
  int v0 = tot[4 * t], v1 = tot[4 * t + 1], v2 = tot[4 * t + 2], v3 = tot[4 * t + 3];
  int tsum = v0 + v1 + v2 + v3;
  s2[t] = tsum; __syncthreads();
  for (int st = 1; st < 256; st <<= 1) {
    int a = (t >= st) ? s2[t - st] : 0; __syncthreads(); s2[t] += a; __syncthreads();
  }
  int ex = s2[t] - tsum;
  gbase[4 * t] = ex;
  gbase[4 * t + 1] = ex + v0;
  gbase[4 * t + 2] = ex + v0 + v1;
  gbase[4 * t + 3] = ex + v0 + v1 + v2;
  if (t == 255) gbase[NBUCK] = ex + tsum;          // == NE
}

// ---- radix pass 3: partition; record = ((src<<10)|dlocal, w_f32bits) single 8B store ----
__global__ __launch_bounds__(256) void k_part(const int* __restrict__ ei, const float* __restrict__ ew,
                                              const int* __restrict__ hist, const int* __restrict__ gbase,
                                              uint2* __restrict__ bsw) {
  __shared__ int cur[NBUCK];
  int t = threadIdx.x, blk = blockIdx.x;
#pragma unroll
  for (int k = 0; k < 4; ++k) {
    int b = t + k * 256;
    cur[b] = gbase[b] + hist[b * PBLK + blk];
  }
  __syncthreads();
  int base = blk * EPB;
  for (int e = base + t; e < base + EPB; e += 256) {
    int src = ei[e];
    int d   = ei[NE + e];
    unsigned wb = __float_as_uint(ew[e]);
    int b = d >> BSH;
    int pos = atomicAdd(&cur[b], 1);
    bsw[pos] = make_uint2(((unsigned)src << BSH) | (unsigned)(d & (NBUCK - 1)), wb);
  }
}

// ------- per-bucket CSR finalize: 1024 blocks, 1024-node buckets, L2-friendly -------
__global__ __launch_bounds__(256) void k_fillD(const int* __restrict__ gbase, const uint2* __restrict__ bsw,
                                               int* __restrict__ rowptr, uint2* __restrict__ colw) {
  __shared__ int loc[NBUCK];      // 1024 node counters (4 KB)
  __shared__ int s2[256];
  int t = threadIdx.x, b = blockIdx.x;
  int beg = gbase[b], end = gbase[b + 1], gb = beg;
  int node_base = b << BSH;
#pragma unroll
  for (int j = 0; j < 4; ++j) loc[t * 4 + j] = 0;
  __syncthreads();
  for (int i = beg + t; i < end; i += 256) atomicAdd(&loc[bsw[i].x & (NBUCK - 1)], 1);
  __syncthreads();
  int v[4]; int tsum = 0;
#pragma unroll
  for (int j = 0; j < 4; ++j) { v[j] = loc[t * 4 + j]; tsum += v[j]; }
  s2[t] = tsum; __syncthreads();
  for (int st = 1; st < 256; st <<= 1) {
    int a = (t >= st) ? s2[t - st] : 0; __syncthreads(); s2[t] += a; __syncthreads();
  }
  int run = s2[t] - tsum;
#pragma unroll
  for (int j = 0; j < 4; ++j) {
    loc[t * 4 + j] = run;
    rowptr[node_base + t * 4 + j] = gb + run;
    run += v[j];
  }
  if (b == NBUCK - 1 && t == 255) rowptr[NN] = NE;
  __syncthreads();
  for (int i = beg + t; i < end; i += 256) {
    uint2 r = bsw[i];
    int p = atomicAdd(&loc[r.x & (NBUCK - 1)], 1);
    colw[gb + p] = make_uint2(r.x >> BSH, r.y);    // (src, w_f32bits)
  }
}

// ---------------- graph rowptr from sorted batch ----------------
__global__ __launch_bounds__(256) void k_gbound(const int* __restrict__ batch, int* __restrict__ gptr) {
  int n = blockIdx.x * 256 + threadIdx.x;
  int b = batch[n];
  int prev = (n == 0) ? -1 : batch[n - 1];
  for (int g = prev + 1; g <= b; ++g) gptr[g] = n;
  if (n == NN - 1) {
    for (int g = b + 1; g <= NG; ++g) gptr[g] = NN;
  }
}

// ------ fused pull-aggregate + MFMA dual-linear + BN stats (EXACT R11/R15 body) ------
__global__ __launch_bounds__(256) void k_agglin(
    const int* __restrict__ rowptr, const uint2* __restrict__ colw,
    const __half* __restrict__ hIn, const float* __restrict__ Wrel,
    const float* __restrict__ brel, const float* __restrict__ Wroot,
    __half* __restrict__ hPre, double* __restrict__ stats) {
  __shared__ __half sA[4][1024];      // per-wave 32x32 f16 agg tile (XOR-swizzled)
  __shared__ uint2 sE[256];           // staged edge records
  __shared__ double rS[256], rQ[256];
  int t = threadIdx.x;
  int wv = t >> 6, lane = t & 63;
  int c = lane & 31, hi = lane >> 5, grp = t >> 5;
  char* myA = (char*)sA[wv];

  // B fragments in registers: B[k][c], k = 16m + hi*8 + j
  half8 bfr[4];
#pragma unroll
  for (int m = 0; m < 4; ++m)
#pragma unroll
    for (int j = 0; j < 8; ++j) {
      int k = 16 * m + hi * 8 + j;
      float w = (k < 32) ? Wrel[c * 32 + k] : Wroot[c * 32 + (k - 32)];
      bfr[m][j] = (_Float16)w;
    }
  float bias = brel[c];
  double aS = 0.0, aQ = 0.0;

  for (int tile = blockIdx.x * 4 + wv; tile < NN / 32; tile += gridDim.x * 4) {
    int nbase = tile * 32;
    // ---- gather: 16 rounds x 2 nodes (one per 32-lane group) ----
    for (int r = 0; r < 16; ++r) {
      int node = 2 * r + hi;
      int n = nbase + node;
      int r0 = rowptr[n], r1 = rowptr[n + 1];
      float acc = 0.f;
      for (int j = r0; j < r1; j += 32) {
        int m_ = r1 - j; if (m_ > 32) m_ = 32;
        uint2 cw = make_uint2(0u, 0u);             // pad: src=0 row, w=+0
        if (c < m_) cw = colw[j + c];
        sE[t] = cw;                                // same-wave LDS
        int mm = (m_ + 7) & ~7;
        for (int i = 0; i < mm; i += 8) {
          const uint4* eb4 = (const uint4*)&sE[grp * 32 + i];
          uint4 q0 = eb4[0], q1 = eb4[1], q2 = eb4[2], q3 = eb4[3];
          // 8 independent 2 B gathers -> 8 loads in flight
          float h0 = __half2float(hIn[(size_t)q0.x * 32 + c]);
          float h1 = __half2float(hIn[(size_t)q0.z * 32 + c]);
          float h2 = __half2float(hIn[(size_t)q1.x * 32 + c]);
          float h3 = __half2float(hIn[(size_t)q1.z * 32 + c]);
          float h4 = __half2float(hIn[(size_t)q2.x * 32 + c]);
          float h5 = __half2float(hIn[(size_t)q2.z * 32 + c]);
          float h6 = __half2float(hIn[(size_t)q3.x * 32 + c]);
          float h7 = __half2float(hIn[(size_t)q3.z * 32 + c]);
          acc = fmaf(__uint_as_float(q0.y), h0, acc);
          acc = fmaf(__uint_as_float(q0.w), h1, acc);
          acc = fmaf(__uint_as_float(q1.y), h2, acc);
          acc = fmaf(__uint_as_float(q1.w), h3, acc);
          acc = fmaf(__uint_as_float(q2.y), h4, acc);
          acc = fmaf(__uint_as_float(q2.w), h5, acc);
          acc = fmaf(__uint_as_float(q3.y), h6, acc);
          acc = fmaf(__uint_as_float(q3.w), h7, acc);
        }
      }
      // write acc to swizzled f16 tile: logical (node, k=c)
      int bw = (node * 64 + c * 2) ^ ((node & 7) << 4);
      *(__half*)(myA + bw) = __float2half(acc);
    }
    // ---- MFMA epilogue (wave-private; same-wave LDS ordering) ----
    f32x16 d;
#pragma unroll
    for (int r = 0; r < 16; ++r) d[r] = bias;
#pragma unroll
    for (int m = 0; m < 4; ++m) {
      half8 a;
      if (m < 2) {
        int node = c;                               // A row = lane&31
        int br = (node * 64 + (16 * m + hi * 8) * 2) ^ ((node & 7) << 4);
        a = *(const half8*)(myA + br);
      } else {
        int chb = 16 * (m - 2) + hi * 8;            // h channel base
        a = *(const half8*)(hIn + (size_t)(nbase + c) * 32 + chb);
      }
      d = __builtin_amdgcn_mfma_f32_32x32x16_f16(a, bfr[m], d, 0, 0, 0);
    }
    // ---- store + BN stats; D: col=lane&31, row=(r&3)+8*(r>>2)+4*hi ----
#pragma unroll
    for (int r = 0; r < 16; ++r) {
      int node = (r & 3) + 8 * (r >> 2) + 4 * hi;
      float v = d[r];
      hPre[(size_t)(nbase + node) * 32 + c] = __float2half(v);
      aS += v; aQ += (double)v * v;
    }
  }
  rS[t] = aS; rQ[t] = aQ;
  __syncthreads();
  for (int s = 128; s >= 32; s >>= 1) {
    if (t < s) { rS[t] += rS[t + s]; rQ[t] += rQ[t + s]; }
    __syncthreads();
  }
  if (t < 32) {
    atomicAdd(&stats[t], rS[t]);
    atomicAdd(&stats[32 + t], rQ[t]);
  }
}

// ---------------- finalize BN ----------------
__global__ void k_bnfin(const double* __restrict__ stats, const float* __restrict__ gamma,
                        const float* __restrict__ beta, float* __restrict__ ss) {
  int c = threadIdx.x;
  double mean = stats[c] * (1.0 / NN);
  double var = stats[32 + c] * (1.0 / NN) - mean * mean;
  float scale = gamma[c] * (float)(1.0 / sqrt(var + 1e-5));
  ss[c] = scale;
  ss[32 + c] = beta[c] - (float)mean * scale;
}

// ---------------- BN apply + ReLU (layer 1) ----------------
__global__ __launch_bounds__(256) void k_apply(const __half* __restrict__ in,
    const float* __restrict__ ss, __half* __restrict__ outp) {
  __shared__ float s0[32], s1[32];
  int t = threadIdx.x;
  if (t < 32) { s0[t] = ss[t]; s1[t] = ss[32 + t]; }
  __syncthreads();
  int idx = blockIdx.x * 256 + t;
  int c = idx & 31;
  float v = fmaxf(fmaf(__half2float(in[idx]), s0[c], s1[c]), 0.f);
  outp[idx] = __float2half(v);
}

// ------- layer-2 BN apply + ReLU + segment-max pool (half2, 4 node-slots) -------
__global__ __launch_bounds__(256) void k_pool(const __half* __restrict__ hB,
    const float* __restrict__ ss, const int* __restrict__ gptr, float* __restrict__ pooled) {
  int t = threadIdx.x;
  int wv = t >> 6, lane = t & 63;
  int p = lane >> 4, cl = lane & 15;          // 4 nodes in flight, 2 ch/lane
  float s0x = ss[2 * cl], s0y = ss[2 * cl + 1];
  float s1x = ss[32 + 2 * cl], s1y = ss[32 + 2 * cl + 1];
  int g = blockIdx.x * 4 + wv;                // grid 4096 x 4 waves = NG exactly
  int a = gptr[g], b = gptr[g + 1];
  float mx = 0.f, my = 0.f;                   // post-ReLU max >= 0
  for (int n = a + p; n < b; n += 4) {
    float2 hv = __half22float2(*(const __half2*)(hB + (size_t)n * 32 + 2 * cl));
    mx = fmaxf(mx, fmaf(hv.x, s0x, s1x));
    my = fmaxf(my, fmaf(hv.y, s0y, s1y));
  }
  mx = fmaxf(mx, __shfl_xor(mx, 16, 64)); my = fmaxf(my, __shfl_xor(my, 16, 64));
  mx = fmaxf(mx, __shfl_xor(mx, 32, 64)); my = fmaxf(my, __shfl_xor(my, 32, 64));
  if (p == 0) *(float2*)&pooled[g * 32 + 2 * cl] = make_float2(mx, my);
}

// ---------------- MLP head ----------------
__global__ __launch_bounds__(256) void k_head(const float* __restrict__ pooled,
    const float* __restrict__ W1, const float* __restrict__ b1,
    const float* __restrict__ W2, const float* __restrict__ b2, float* __restrict__ out) {
  __shared__ float sW1[64 * 33], sW2[10 * 65], sb1[64], sb2[10];
  __shared__ float sHid[4][64];
  int t = threadIdx.x;
  for (int i = t; i < 2048; i += 256) sW1[(i >> 5) * 33 + (i & 31)] = W1[i];
  for (int i = t; i < 640; i += 256) sW2[(i >> 6) * 65 + (i & 63)] = W2[i];
  if (t < 64) sb1[t] = b1[t];
  if (t < 10) sb2[t] = b2[t];
  __syncthreads();
  int w = t >> 6, lane = t & 63;
  for (int g = blockIdx.x * 4 + w; g < NG; g += gridDim.x * 4) {
    float pv = (lane < 32) ? pooled[g * 32 + lane] : 0.f;
    float acc = sb1[lane];
#pragma unroll
    for (int k = 0; k < 32; ++k)
      acc = fmaf(__shfl(pv, k, 64), sW1[lane * 33 + k], acc);
    acc = fmaxf(acc, 0.f);
    sHid[w][lane] = acc;
    __syncthreads();
    if (lane < 10) {
      float o = sb2[lane];
#pragma unroll
      for (int j = 0; j < 64; ++j) o = fmaf(sHid[w][j], sW2[lane * 65 + j], o);
      out[g * 10 + lane] = o;
    }
    __syncthreads();
  }
}

extern "C" void kernel_launch(void* const* d_in, const int* in_sizes, int n_in,
                              void* d_out, int out_size, void* d_ws, size_t ws_size,
                              hipStream_t stream) {
  const float* x      = (const float*)d_in[0];
  const int*   ei     = (const int*)d_in[1];
  const float* ea     = (const float*)d_in[2];
  const int*   batch  = (const int*)d_in[3];
  const float* W_emb  = (const float*)d_in[4];
  const float* b_emb  = (const float*)d_in[5];
  const float* W_rel  = (const float*)d_in[6];
  const float* b_rel  = (const float*)d_in[7];
  const float* W_root = (const float*)d_in[8];
  const float* gamma  = (const float*)d_in[9];
  const float* beta   = (const float*)d_in[10];
  const float* W1     = (const float*)d_in[11];
  const float* b1     = (const float*)d_in[12];
  const float* W2     = (const float*)d_in[13];
  const float* b2     = (const float*)d_in[14];
  float* out = (float*)d_out;

  // ---- workspace layout (~201 MiB of 256 MiB) ----
  char* ws = (char*)d_ws;
  size_t off = 0;
  __half* hA    = (__half*)(ws + off); off += (size_t)NN * 32 * 2;          // 64 MiB
  uint2*  colw  = (uint2*)(ws + off);  off += (size_t)NE * 8;               // 64 MiB
  uint2*  bsw   = (uint2*)(ws + off);                                        // 64 MiB
  __half* hB    = (__half*)(ws + off);                                       // ALIASES bsw (dead before hB written)
  off += (size_t)NE * 8;
  int*    rowptr= (int*)(ws + off);    off += ((size_t)NN + 64) * 4;        // 4 MiB
  int*    hist  = (int*)(ws + off);    off += (size_t)NBUCK * PBLK * 4;     // 1 MiB
  int*    tot   = (int*)(ws + off);    off += NBUCK * 4;                    // 4 KiB
  int*    gbase = (int*)(ws + off);    off += (NBUCK + 64) * 4;             // ~4 KiB
  int*    gptr  = (int*)(ws + off);    off += ((size_t)NG + 64) * 4;
  float*  pooled= (float*)(ws + off);
  double* stats = (double*)d_out;                   // overwritten by k_head later
  float*  ss0   = (float*)((char*)d_out + 512);
  float*  ss1   = (float*)((char*)d_out + 768);

  k_embed<<<NN * 32 / 256, 256, 0, stream>>>(x, W_emb, b_emb, hA);

  // ---- radix-partition CSR build (1024 buckets) ----
  k_pcnt <<<PBLK, 256, 0, stream>>>(ei + NE, hist);
  k_scanA<<<NBUCK, 256, 0, stream>>>(hist, tot);
  k_scanB<<<1, 256, 0, stream>>>(tot, gbase);
  k_part <<<PBLK, 256, 0, stream>>>(ei, ea, hist, gbase, bsw);
  k_fillD<<<NBUCK, 256, 0, stream>>>(gbase, bsw, rowptr, colw);
  k_gbound<<<NN / 256, 256, 0, stream>>>(batch, gptr);

  // ---- layer 1: agglin(hA -> hB), BN stats, apply BN+ReLU (hB -> hA) ----
  (void)hipMemsetAsync(stats, 0, 64 * 8, stream);
  k_agglin<<<2048, 256, 0, stream>>>(rowptr, colw, hA, W_rel, b_rel, W_root, hB, stats);
  k_bnfin<<<1, 32, 0, stream>>>(stats, gamma, beta, ss0);
  k_apply<<<NN * 32 / 256, 256, 0, stream>>>(hB, ss0, hA);

  // ---- layer 2: agglin(hA -> hB), BN stats, fused pool ----
  (void)hipMemsetAsync(stats, 0, 64 * 8, stream);
  k_agglin<<<2048, 256, 0, stream>>>(rowptr, colw, hA, W_rel + 1024, b_rel + 32,
                                     W_root + 1024, hB, stats);
  k_bnfin<<<1, 32, 0, stream>>>(stats, gamma + 32, beta + 32, ss1);

  k_pool<<<NG / 4, 256, 0, stream>>>(hB, ss1, gptr, pooled);
  k_head<<<1024, 256, 0, stream>>>(pooled, W1, b1, W2, b2, out);
}